// Round 1
// baseline (1191.644 us; speedup 1.0000x reference)
//
#include <hip/hip_runtime.h>
#include <math.h>

#define H 256

// ---------------- helpers ----------------
__global__ void k_zero(int* __restrict__ p, int nwords) {
    int i = blockIdx.x * blockDim.x + threadIdx.x;
    if (i < nwords) p[i] = 0;
}

// count in-degree on dst (self-loop added later as +1)
__global__ void k_count(const int* __restrict__ ei, int* __restrict__ deg, int E) {
    int e = blockIdx.x * blockDim.x + threadIdx.x;
    if (e < E) atomicAdd(&deg[ei[E + e]], 1);
}

__global__ void k_dinv(const int* __restrict__ deg, float* __restrict__ dinv, int n) {
    int i = blockIdx.x * blockDim.x + threadIdx.x;
    if (i < n) dinv[i] = rsqrtf((float)(deg[i] + 1));
}

// ---------------- exclusive scan (3 kernels) ----------------
#define SCAN_B 512
__global__ void k_scan1(const int* __restrict__ deg, int* __restrict__ row_part,
                        int* __restrict__ bsum, int n) {
    __shared__ int sm[SCAN_B];
    int t = threadIdx.x;
    int i = blockIdx.x * SCAN_B + t;
    int v = (i < n) ? deg[i] : 0;
    sm[t] = v;
    __syncthreads();
    for (int off = 1; off < SCAN_B; off <<= 1) {
        int add = (t >= off) ? sm[t - off] : 0;
        __syncthreads();
        sm[t] += add;
        __syncthreads();
    }
    if (i < n) row_part[i] = sm[t] - v;          // exclusive within block
    if (t == SCAN_B - 1) bsum[blockIdx.x] = sm[t];
}

__global__ void k_scan2(const int* __restrict__ bsum, int* __restrict__ boff, int nb) {
    __shared__ int sm[1024];
    int t = threadIdx.x;
    int v = (t < nb) ? bsum[t] : 0;
    sm[t] = v;
    __syncthreads();
    for (int off = 1; off < 1024; off <<= 1) {
        int add = (t >= off) ? sm[t - off] : 0;
        __syncthreads();
        sm[t] += add;
        __syncthreads();
    }
    if (t < nb) boff[t] = sm[t] - v;             // exclusive
    if (t == 1023) boff[nb] = sm[t];             // grand total
}

__global__ void k_scan3(int* __restrict__ row_off, const int* __restrict__ row_part,
                        const int* __restrict__ boff, int n, int nb) {
    int i = blockIdx.x * blockDim.x + threadIdx.x;
    if (i < n) row_off[i] = row_part[i] + boff[i >> 9];
    else if (i == n) row_off[n] = boff[nb];
}

__global__ void k_fill(const int* __restrict__ ei, int* __restrict__ cursor,
                       const int* __restrict__ row_off, int* __restrict__ csr, int E) {
    int e = blockIdx.x * blockDim.x + threadIdx.x;
    if (e >= E) return;
    int src = ei[e];
    int dst = ei[E + e];
    int pos = atomicAdd(&cursor[dst], 1);
    csr[row_off[dst] + pos] = src;
}

// ---------------- layer 1: x (N x 3) @ W1 (3 x 256), scaled by dinv[row] ----------------
__global__ void k_layer1(const float* __restrict__ x, const float* __restrict__ W1,
                         const float* __restrict__ dinv, float* __restrict__ out, int n) {
    int node = blockIdx.x;
    if (node >= n) return;
    int c = threadIdx.x;
    float x0 = x[node * 3 + 0], x1 = x[node * 3 + 1], x2 = x[node * 3 + 2];
    float v = x0 * W1[c] + x1 * W1[H + c] + x2 * W1[2 * H + c];
    out[node * H + c] = v * dinv[node];
}

// ---------------- GEMM: out = (A @ W) * dinv[row];  A: n x 256, W: 256 x 256 ----------------
// block 256 threads computes 64 rows x 256 cols
#define BM 64
#define KB 32
__global__ __launch_bounds__(256, 2)
void k_gemm(const float* __restrict__ A, const float* __restrict__ W,
            const float* __restrict__ dinv, float* __restrict__ out, int n) {
    __shared__ float As[BM][KB];     // 8 KB
    __shared__ float Bs[KB][H];      // 32 KB
    const int tid = threadIdx.x;
    const int tc = tid & 63;         // col group: cols 4*tc .. 4*tc+3
    const int tr = tid >> 6;         // row group: rows tr*16 .. tr*16+15
    const int block_row = blockIdx.x * BM;

    float acc[16][4];
#pragma unroll
    for (int r = 0; r < 16; r++)
#pragma unroll
        for (int j = 0; j < 4; j++) acc[r][j] = 0.f;

    for (int k0 = 0; k0 < H; k0 += KB) {
        // stage A tile: 64 x 32 = 512 float4; 2 per thread
#pragma unroll
        for (int q = 0; q < 2; q++) {
            int s = tid + q * 256;
            int r = s >> 3, c4 = s & 7;
            int grow = block_row + r;
            float4 v = make_float4(0.f, 0.f, 0.f, 0.f);
            if (grow < n) v = *reinterpret_cast<const float4*>(&A[(size_t)grow * H + k0 + c4 * 4]);
            As[r][c4 * 4 + 0] = v.x; As[r][c4 * 4 + 1] = v.y;
            As[r][c4 * 4 + 2] = v.z; As[r][c4 * 4 + 3] = v.w;
        }
        // stage B tile: 32 x 256 = 2048 float4; 8 per thread
#pragma unroll
        for (int q = 0; q < 8; q++) {
            int s = tid + q * 256;
            int r = s >> 6, c4 = s & 63;
            float4 v = *reinterpret_cast<const float4*>(&W[(size_t)(k0 + r) * H + c4 * 4]);
            *reinterpret_cast<float4*>(&Bs[r][c4 * 4]) = v;
        }
        __syncthreads();
#pragma unroll
        for (int kk = 0; kk < KB; kk++) {
            float4 bv = *reinterpret_cast<const float4*>(&Bs[kk][tc * 4]);
            float a[16];
#pragma unroll
            for (int r = 0; r < 16; r++) a[r] = As[tr * 16 + r][kk];  // wave-uniform broadcast
#pragma unroll
            for (int r = 0; r < 16; r++) {
                acc[r][0] = fmaf(a[r], bv.x, acc[r][0]);
                acc[r][1] = fmaf(a[r], bv.y, acc[r][1]);
                acc[r][2] = fmaf(a[r], bv.z, acc[r][2]);
                acc[r][3] = fmaf(a[r], bv.w, acc[r][3]);
            }
        }
        __syncthreads();
    }
#pragma unroll
    for (int r = 0; r < 16; r++) {
        int grow = block_row + tr * 16 + r;
        if (grow < n) {
            float d = dinv[grow];
            float4 o = make_float4(acc[r][0] * d, acc[r][1] * d, acc[r][2] * d, acc[r][3] * d);
            *reinterpret_cast<float4*>(&out[(size_t)grow * H + tc * 4]) = o;
        }
    }
}

// ---------------- aggregation: out = relu(dinv[i]*(sum_in hws[src] + hws[i]) + b) ----------------
// one wave per node; lane handles float4 at 4*lane
__global__ void k_agg(const float* __restrict__ hws, const int* __restrict__ row_off,
                      const int* __restrict__ csr, const float* __restrict__ dinv,
                      const float* __restrict__ bias, float* __restrict__ out, int n) {
    int node = blockIdx.x * 4 + (threadIdx.x >> 6);
    if (node >= n) return;
    int lane = threadIdx.x & 63;
    const float4* self = reinterpret_cast<const float4*>(&hws[(size_t)node * H]);
    float4 acc = self[lane];
    int s = row_off[node], e = row_off[node + 1];
    for (int k = s; k < e; k++) {
        int src = csr[k];
        float4 v = reinterpret_cast<const float4*>(&hws[(size_t)src * H])[lane];
        acc.x += v.x; acc.y += v.y; acc.z += v.z; acc.w += v.w;
    }
    float d = dinv[node];
    float4 b = reinterpret_cast<const float4*>(bias)[lane];
    float4 o;
    o.x = fmaxf(acc.x * d + b.x, 0.f);
    o.y = fmaxf(acc.y * d + b.y, 0.f);
    o.z = fmaxf(acc.z * d + b.z, 0.f);
    o.w = fmaxf(acc.w * d + b.w, 0.f);
    reinterpret_cast<float4*>(&out[(size_t)node * H])[lane] = o;
}

// ---------------- pooling: batch is sorted; block handles contiguous node range ----------------
__global__ void k_pool(const float* __restrict__ h, const int* __restrict__ batch,
                       float* __restrict__ pooled, float* __restrict__ counts, int n) {
    int nb = gridDim.x;
    int per = (n + nb - 1) / nb;
    int s = blockIdx.x * per;
    int e = min(n, s + per);
    if (s >= e) return;
    int t = threadIdx.x;
    float acc = 0.f;
    int cur = batch[s];
    int cnt = 0;
    for (int i = s; i < e; i++) {
        int g = batch[i];
        if (g != cur) {
            atomicAdd(&pooled[cur * H + t], acc);
            if (t == 0) atomicAdd(&counts[cur], (float)cnt);
            acc = 0.f; cnt = 0; cur = g;
        }
        acc += h[(size_t)i * H + t];
        cnt++;
    }
    atomicAdd(&pooled[cur * H + t], acc);
    if (t == 0) atomicAdd(&counts[cur], (float)cnt);
}

// ---------------- output head: sigmoid(pooled/count @ Wout + bout) ----------------
__global__ void k_out(const float* __restrict__ pooled, const float* __restrict__ counts,
                      const float* __restrict__ Wout, const float* __restrict__ bout,
                      float* __restrict__ out, int G) {
    int t = threadIdx.x;
    if (t >= G * 2) return;
    int g = t >> 1, c = t & 1;
    float s = 0.f;
    for (int k = 0; k < H; k++) s = fmaf(pooled[g * H + k], Wout[k * 2 + c], s);
    float cnt = fmaxf(counts[g], 1.0f);
    float logit = s / cnt + bout[c];
    out[g * 2 + c] = 1.f / (1.f + expf(-logit));
}

// ---------------- launch ----------------
extern "C" void kernel_launch(void* const* d_in, const int* in_sizes, int n_in,
                              void* d_out, int out_size, void* d_ws, size_t ws_size,
                              hipStream_t stream) {
    const float* x    = (const float*)d_in[0];
    const int*   ei   = (const int*)d_in[1];
    const int*   batch= (const int*)d_in[2];
    const float* W1   = (const float*)d_in[3];
    const float* b1   = (const float*)d_in[4];
    const float* Ws[4] = {(const float*)d_in[5], (const float*)d_in[7],
                          (const float*)d_in[9], (const float*)d_in[11]};
    const float* bs[4] = {(const float*)d_in[6], (const float*)d_in[8],
                          (const float*)d_in[10], (const float*)d_in[12]};
    const float* Wout = (const float*)d_in[13];
    const float* bout = (const float*)d_in[14];

    const int N = in_sizes[0] / 3;
    const int E = in_sizes[1] / 2;
    const int G = out_size / 2;

    // workspace carve (zeroed region first)
    char* p = (char*)d_ws;
    auto alloc = [&](size_t bytes) { char* r = p; p += (bytes + 255) & ~(size_t)255; return r; };
    int*   deg      = (int*)alloc((size_t)N * 4);
    int*   cursor   = (int*)alloc((size_t)N * 4);
    float* counts   = (float*)alloc((size_t)G * 4);
    float* pooled   = (float*)alloc((size_t)G * H * 4);
    size_t zero_words = ((char*)p - (char*)d_ws) / 4;
    float* dinv     = (float*)alloc((size_t)N * 4);
    int*   row_part = (int*)alloc((size_t)N * 4);
    int*   row_off  = (int*)alloc((size_t)(N + 1) * 4);
    int*   bsum     = (int*)alloc(1024 * 4);
    int*   boff     = (int*)alloc(1025 * 4);
    int*   csr      = (int*)alloc((size_t)E * 4);
    float* bufA     = (float*)alloc((size_t)N * H * 4);
    float* bufB     = (float*)alloc((size_t)N * H * 4);

    k_zero<<<(int)((zero_words + 255) / 256), 256, 0, stream>>>((int*)d_ws, (int)zero_words);
    k_count<<<(E + 255) / 256, 256, 0, stream>>>(ei, deg, E);
    k_dinv<<<(N + 255) / 256, 256, 0, stream>>>(deg, dinv, N);

    int nb = (N + SCAN_B - 1) / SCAN_B;
    k_scan1<<<nb, SCAN_B, 0, stream>>>(deg, row_part, bsum, N);
    k_scan2<<<1, 1024, 0, stream>>>(bsum, boff, nb);
    k_scan3<<<(N + 1 + 255) / 256, 256, 0, stream>>>(row_off, row_part, boff, N, nb);
    k_fill<<<(E + 255) / 256, 256, 0, stream>>>(ei, cursor, row_off, csr, E);

    // layer 1
    k_layer1<<<N, 256, 0, stream>>>(x, W1, dinv, bufB, N);
    k_agg<<<(N + 3) / 4, 256, 0, stream>>>(bufB, row_off, csr, dinv, b1, bufA, N);

    // layers 2..5
    for (int l = 0; l < 4; l++) {
        k_gemm<<<(N + BM - 1) / BM, 256, 0, stream>>>(bufA, Ws[l], dinv, bufB, N);
        k_agg<<<(N + 3) / 4, 256, 0, stream>>>(bufB, row_off, csr, dinv, bs[l], bufA, N);
    }

    // pool + head
    k_pool<<<1024, 256, 0, stream>>>(bufA, batch, pooled, counts, N);
    k_out<<<1, 256, 0, stream>>>(pooled, counts, Wout, bout, (float*)d_out, G);
}

// Round 2
// 561.548 us; speedup vs baseline: 2.1221x; 2.1221x over previous
//
#include <hip/hip_runtime.h>
#include <math.h>
#include <stdint.h>

#define H 256

typedef __attribute__((ext_vector_type(4))) float f32x4;
typedef __attribute__((ext_vector_type(8))) short bf16x8;

__device__ __forceinline__ float b2f(ushort h) { return __uint_as_float(((uint32_t)h) << 16); }
__device__ __forceinline__ ushort f2bf(float f) {
    uint32_t u = __float_as_uint(f);
    u = (u + 0x7FFF + ((u >> 16) & 1)) >> 16;   // RNE
    return (ushort)u;
}

// async global->LDS, 16B per lane; lds base must be wave-uniform
__device__ __forceinline__ void gload_lds16(const void* g, void* l) {
    __builtin_amdgcn_global_load_lds(
        (__attribute__((address_space(1))) void*)(uintptr_t)g,
        (__attribute__((address_space(3))) void*)(uint32_t)(uintptr_t)l,
        16, 0, 0);
}

// ---------------- helpers ----------------
__global__ void k_zero(int* __restrict__ p, int nwords) {
    int i = blockIdx.x * blockDim.x + threadIdx.x;
    if (i < nwords) p[i] = 0;
}

__global__ void k_count(const int* __restrict__ ei, int* __restrict__ deg, int E) {
    int e = blockIdx.x * blockDim.x + threadIdx.x;
    if (e < E) atomicAdd(&deg[ei[E + e]], 1);
}

__global__ void k_dinv(const int* __restrict__ deg, float* __restrict__ dinv, int n) {
    int i = blockIdx.x * blockDim.x + threadIdx.x;
    if (i < n) dinv[i] = rsqrtf((float)(deg[i] + 1));
}

// ---------------- exclusive scan ----------------
#define SCAN_B 512
__global__ void k_scan1(const int* __restrict__ deg, int* __restrict__ row_part,
                        int* __restrict__ bsum, int n) {
    __shared__ int sm[SCAN_B];
    int t = threadIdx.x;
    int i = blockIdx.x * SCAN_B + t;
    int v = (i < n) ? deg[i] : 0;
    sm[t] = v;
    __syncthreads();
    for (int off = 1; off < SCAN_B; off <<= 1) {
        int add = (t >= off) ? sm[t - off] : 0;
        __syncthreads();
        sm[t] += add;
        __syncthreads();
    }
    if (i < n) row_part[i] = sm[t] - v;
    if (t == SCAN_B - 1) bsum[blockIdx.x] = sm[t];
}

__global__ void k_scan2(const int* __restrict__ bsum, int* __restrict__ boff, int nb) {
    __shared__ int sm[1024];
    int t = threadIdx.x;
    int v = (t < nb) ? bsum[t] : 0;
    sm[t] = v;
    __syncthreads();
    for (int off = 1; off < 1024; off <<= 1) {
        int add = (t >= off) ? sm[t - off] : 0;
        __syncthreads();
        sm[t] += add;
        __syncthreads();
    }
    if (t < nb) boff[t] = sm[t] - v;
    if (t == 1023) boff[nb] = sm[t];
}

__global__ void k_scan3(int* __restrict__ row_off, const int* __restrict__ row_part,
                        const int* __restrict__ boff, int n, int nb) {
    int i = blockIdx.x * blockDim.x + threadIdx.x;
    if (i < n) row_off[i] = row_part[i] + boff[i >> 9];
    else if (i == n) row_off[n] = boff[nb];
}

__global__ void k_fill(const int* __restrict__ ei, int* __restrict__ cursor,
                       const int* __restrict__ row_off, int* __restrict__ csr, int E) {
    int e = blockIdx.x * blockDim.x + threadIdx.x;
    if (e >= E) return;
    int src = ei[e];
    int dst = ei[E + e];
    int pos = atomicAdd(&cursor[dst], 1);
    csr[row_off[dst] + pos] = src;
}

// ---------------- W -> Wt (transposed, bf16) ----------------
__global__ void k_wprep(const float* __restrict__ W, ushort* __restrict__ Wt) {
    int idx = blockIdx.x * 256 + threadIdx.x;   // 0..65535
    int k = idx >> 8, nn = idx & 255;
    Wt[nn * 256 + k] = f2bf(W[idx]);            // Wt[n][k] = W[k][n]
}

// ---------------- layer 1 ----------------
__global__ void k_layer1(const float* __restrict__ x, const float* __restrict__ W1,
                         const float* __restrict__ dinv, ushort* __restrict__ out, int n) {
    int node = blockIdx.x;
    if (node >= n) return;
    int c = threadIdx.x;
    float x0 = x[node * 3 + 0], x1 = x[node * 3 + 1], x2 = x[node * 3 + 2];
    float v = x0 * W1[c] + x1 * W1[H + c] + x2 * W1[2 * H + c];
    out[(size_t)node * H + c] = f2bf(v * dinv[node]);
}

// ---------------- MFMA GEMM: out = bf16((A @ W) * dinv[row]) ----------------
// A bf16 [padN][256], Wt bf16 [256][256] (Wt[n][k] = W[k][n]). 128x128 tile, BK=32.
__global__ __launch_bounds__(256, 2)
void k_gemm(const ushort* __restrict__ A, const ushort* __restrict__ Wt,
            const float* __restrict__ dinv, ushort* __restrict__ out, int n) {
    // [buf][A/B][kgroup][row][8] : conflict-free ds_read_b128, linear for global_load_lds
    __shared__ ushort lds[2][2][4][128][8];
    const int tid  = threadIdx.x;
    const int lane = tid & 63;
    const int w    = tid >> 6;
    const int row0 = ((int)blockIdx.x >> 1) * 128;
    const int col0 = ((int)blockIdx.x & 1) * 128;
    const int wm   = (w & 1) * 64;
    const int wn   = (w >> 1) * 64;
    const int g    = lane >> 4;
    const int r15  = lane & 15;

    f32x4 acc[4][4] = {};

    auto stage = [&](int buf, int k0) {
#pragma unroll
        for (int q = 0; q < 2; q++) {
            int ii = w * 2 + q;             // 8 chunks of 1KB each for A and for B
            int gg = ii >> 1, half = ii & 1;
            gload_lds16(A  + (size_t)(row0 + half * 64 + lane) * H + k0 + gg * 8,
                        &lds[buf][0][gg][half * 64][0]);
            gload_lds16(Wt + (size_t)(col0 + half * 64 + lane) * H + k0 + gg * 8,
                        &lds[buf][1][gg][half * 64][0]);
        }
    };

    stage(0, 0);
    for (int t = 0; t < 8; t++) {
        __syncthreads();                     // drains vmcnt: stage(t) complete
        if (t < 7) stage((t + 1) & 1, (t + 1) * 32);
        const int b = t & 1;
        bf16x8 af[4], bfr[4];
#pragma unroll
        for (int m = 0; m < 4; m++)
            af[m] = *(const bf16x8*)&lds[b][0][g][wm + m * 16 + r15][0];
#pragma unroll
        for (int nn = 0; nn < 4; nn++)
            bfr[nn] = *(const bf16x8*)&lds[b][1][g][wn + nn * 16 + r15][0];
#pragma unroll
        for (int m = 0; m < 4; m++)
#pragma unroll
            for (int nn = 0; nn < 4; nn++)
                acc[m][nn] = __builtin_amdgcn_mfma_f32_16x16x32_bf16(af[m], bfr[nn], acc[m][nn], 0, 0, 0);
    }

    // epilogue: C/D layout col = lane&15, row = (lane>>4)*4 + reg
#pragma unroll
    for (int m = 0; m < 4; m++) {
#pragma unroll
        for (int j = 0; j < 4; j++) {
            int grow = row0 + wm + m * 16 + (lane >> 4) * 4 + j;
            if (grow < n) {
                float d = dinv[grow];
#pragma unroll
                for (int nn = 0; nn < 4; nn++) {
                    int gcol = col0 + wn + nn * 16 + r15;
                    out[(size_t)grow * H + gcol] = f2bf(acc[m][nn][j] * d);
                }
            }
        }
    }
}

// ---------------- aggregation: out = bf16(relu(dinv[i]*(sum_in hws[src] + hws[i]) + b)) ----------------
__global__ void k_agg(const ushort* __restrict__ hws, const int* __restrict__ row_off,
                      const int* __restrict__ csr, const float* __restrict__ dinv,
                      const float* __restrict__ bias, ushort* __restrict__ out, int n) {
    int node = blockIdx.x * 4 + (threadIdx.x >> 6);
    if (node >= n) return;
    int lane = threadIdx.x & 63;
    ushort4 sv = ((const ushort4*)(hws + (size_t)node * H))[lane];
    float a0 = b2f(sv.x), a1 = b2f(sv.y), a2 = b2f(sv.z), a3 = b2f(sv.w);
    int s = row_off[node], e = row_off[node + 1];
    for (int k = s; k < e; k++) {
        int src = csr[k];
        ushort4 v = ((const ushort4*)(hws + (size_t)src * H))[lane];
        a0 += b2f(v.x); a1 += b2f(v.y); a2 += b2f(v.z); a3 += b2f(v.w);
    }
    float d = dinv[node];
    float4 b = ((const float4*)bias)[lane];
    ushort4 o;
    o.x = f2bf(fmaxf(a0 * d + b.x, 0.f));
    o.y = f2bf(fmaxf(a1 * d + b.y, 0.f));
    o.z = f2bf(fmaxf(a2 * d + b.z, 0.f));
    o.w = f2bf(fmaxf(a3 * d + b.w, 0.f));
    ((ushort4*)(out + (size_t)node * H))[lane] = o;
}

// ---------------- pooling ----------------
__global__ void k_pool(const ushort* __restrict__ h, const int* __restrict__ batch,
                       float* __restrict__ pooled, float* __restrict__ counts, int n) {
    int nb = gridDim.x;
    int per = (n + nb - 1) / nb;
    int s = blockIdx.x * per;
    int e = min(n, s + per);
    if (s >= e) return;
    int t = threadIdx.x;
    float acc = 0.f;
    int cur = batch[s];
    int cnt = 0;
    for (int i = s; i < e; i++) {
        int g = batch[i];
        if (g != cur) {
            atomicAdd(&pooled[cur * H + t], acc);
            if (t == 0) atomicAdd(&counts[cur], (float)cnt);
            acc = 0.f; cnt = 0; cur = g;
        }
        acc += b2f(h[(size_t)i * H + t]);
        cnt++;
    }
    atomicAdd(&pooled[cur * H + t], acc);
    if (t == 0) atomicAdd(&counts[cur], (float)cnt);
}

// ---------------- head ----------------
__global__ void k_out(const float* __restrict__ pooled, const float* __restrict__ counts,
                      const float* __restrict__ Wout, const float* __restrict__ bout,
                      float* __restrict__ out, int G) {
    int t = threadIdx.x;
    if (t >= G * 2) return;
    int g = t >> 1, c = t & 1;
    float s = 0.f;
    for (int k = 0; k < H; k++) s = fmaf(pooled[g * H + k], Wout[k * 2 + c], s);
    float cnt = fmaxf(counts[g], 1.0f);
    float logit = s / cnt + bout[c];
    out[g * 2 + c] = 1.f / (1.f + expf(-logit));
}

// ---------------- launch ----------------
extern "C" void kernel_launch(void* const* d_in, const int* in_sizes, int n_in,
                              void* d_out, int out_size, void* d_ws, size_t ws_size,
                              hipStream_t stream) {
    const float* x    = (const float*)d_in[0];
    const int*   ei   = (const int*)d_in[1];
    const int*   batch= (const int*)d_in[2];
    const float* W1   = (const float*)d_in[3];
    const float* b1   = (const float*)d_in[4];
    const float* Ws[4] = {(const float*)d_in[5], (const float*)d_in[7],
                          (const float*)d_in[9], (const float*)d_in[11]};
    const float* bs[4] = {(const float*)d_in[6], (const float*)d_in[8],
                          (const float*)d_in[10], (const float*)d_in[12]};
    const float* Wout = (const float*)d_in[13];
    const float* bout = (const float*)d_in[14];

    const int N = in_sizes[0] / 3;
    const int E = in_sizes[1] / 2;
    const int G = out_size / 2;
    const int padN = ((N + 127) / 128) * 128;

    char* p = (char*)d_ws;
    auto alloc = [&](size_t bytes) { char* r = p; p += (bytes + 255) & ~(size_t)255; return r; };
    int*    deg      = (int*)alloc((size_t)N * 4);
    int*    cursor   = (int*)alloc((size_t)N * 4);
    float*  counts   = (float*)alloc((size_t)G * 4);
    float*  pooled   = (float*)alloc((size_t)G * H * 4);
    size_t zero_words = ((char*)p - (char*)d_ws) / 4;
    float*  dinv     = (float*)alloc((size_t)N * 4);
    int*    row_part = (int*)alloc((size_t)N * 4);
    int*    row_off  = (int*)alloc((size_t)(N + 1) * 4);
    int*    bsum     = (int*)alloc(1024 * 4);
    int*    boff     = (int*)alloc(1025 * 4);
    int*    csr      = (int*)alloc((size_t)E * 4);
    ushort* Wt       = (ushort*)alloc((size_t)4 * H * H * 2);
    ushort* bufA     = (ushort*)alloc((size_t)padN * H * 2);
    ushort* bufB     = (ushort*)alloc((size_t)padN * H * 2);

    k_zero<<<(int)((zero_words + 255) / 256), 256, 0, stream>>>((int*)d_ws, (int)zero_words);
    k_count<<<(E + 255) / 256, 256, 0, stream>>>(ei, deg, E);
    k_dinv<<<(N + 255) / 256, 256, 0, stream>>>(deg, dinv, N);

    int nb = (N + SCAN_B - 1) / SCAN_B;
    k_scan1<<<nb, SCAN_B, 0, stream>>>(deg, row_part, bsum, N);
    k_scan2<<<1, 1024, 0, stream>>>(bsum, boff, nb);
    k_scan3<<<(N + 1 + 255) / 256, 256, 0, stream>>>(row_off, row_part, boff, N, nb);
    k_fill<<<(E + 255) / 256, 256, 0, stream>>>(ei, cursor, row_off, csr, E);

    for (int l = 0; l < 4; l++)
        k_wprep<<<H * H / 256, 256, 0, stream>>>(Ws[l], Wt + (size_t)l * H * H);

    // layer 1
    k_layer1<<<N, 256, 0, stream>>>(x, W1, dinv, bufB, N);
    k_agg<<<(N + 3) / 4, 256, 0, stream>>>(bufB, row_off, csr, dinv, b1, bufA, N);

    // layers 2..5 (MFMA)
    for (int l = 0; l < 4; l++) {
        k_gemm<<<(padN / 128) * 2, 256, 0, stream>>>(bufA, Wt + (size_t)l * H * H, dinv, bufB, N);
        k_agg<<<(N + 3) / 4, 256, 0, stream>>>(bufB, row_off, csr, dinv, bs[l], bufA, N);
    }

    k_pool<<<1024, 256, 0, stream>>>(bufA, batch, pooled, counts, N);
    k_out<<<1, 256, 0, stream>>>(pooled, counts, Wout, bout, (float*)d_out, G);
}